// Round 1
// 1046.521 us; speedup vs baseline: 1.1708x; 1.1708x over previous
//
#include <hip/hip_runtime.h>
#include <hip/hip_bf16.h>
#include <math.h>

// Problem constants
namespace {
constexpr int Bn = 8;
constexpr int Hn = 16;
constexpr int Ln = 512;
constexpr int HD = 64;
constexpr int DM = 1024;
constexpr int TL = 1024;  // 2*L
constexpr size_t QS  = (size_t)Bn * Hn * Ln * HD;  // 4,194,304 floats per q/k/v
constexpr size_t FSz = (size_t)Hn * Ln * TL;       // 8,388,608 floats per-batch F (or G)
constexpr size_t WN  = (size_t)DM * 3 * DM;        // 3,145,728 W elements
}

typedef __bf16 bf16x8 __attribute__((ext_vector_type(8)));
typedef float f32x4 __attribute__((ext_vector_type(4)));

typedef __attribute__((address_space(1))) void as1_void_t;
typedef __attribute__((address_space(3))) void as3_void_t;

__device__ __forceinline__ void gload_lds16(const void* g, void* l) {
  // global -> LDS direct DMA, 16B per lane; LDS dest = wave-uniform base + lane*16
  __builtin_amdgcn_global_load_lds((as1_void_t*)g, (as3_void_t*)l, 16, 0, 0);
}

__device__ __forceinline__ unsigned short f2bf(float f) {
  unsigned int u = __float_as_uint(f);
  u += 0x7fffu + ((u >> 16) & 1u);  // round-to-nearest-even
  return (unsigned short)(u >> 16);
}
__device__ __forceinline__ float bf2f(unsigned short h) {
  return __uint_as_float(((unsigned int)h) << 16);
}

// ---------------------------------------------------------------------------
// conv_x: x (fp32 [4096][1024]) -> xh, xl (bf16 hi/lo, same layout)
// ---------------------------------------------------------------------------
__global__ __launch_bounds__(256) void conv_x(const float* __restrict__ x,
                                              unsigned short* __restrict__ xh,
                                              unsigned short* __restrict__ xl) {
  size_t i = ((size_t)blockIdx.x * 256 + threadIdx.x) * 4;
  float4 v = *(const float4*)(x + i);
  unsigned short h0 = f2bf(v.x), h1 = f2bf(v.y), h2 = f2bf(v.z), h3 = f2bf(v.w);
  ushort4 hv = make_ushort4(h0, h1, h2, h3);
  ushort4 lv = make_ushort4(f2bf(v.x - bf2f(h0)), f2bf(v.y - bf2f(h1)),
                            f2bf(v.z - bf2f(h2)), f2bf(v.w - bf2f(h3)));
  *(ushort4*)(xh + i) = hv;
  *(ushort4*)(xl + i) = lv;
}

// ---------------------------------------------------------------------------
// conv_w: W (fp32 [1024][3072]) -> whT, wlT (bf16 hi/lo, TRANSPOSED [3072][1024])
// 64x64 tile via LDS transpose.
// ---------------------------------------------------------------------------
__global__ __launch_bounds__(256) void conv_w(const float* __restrict__ W,
                                              unsigned short* __restrict__ wh,
                                              unsigned short* __restrict__ wl) {
  __shared__ unsigned short Th[64][72];
  __shared__ unsigned short Tl[64][72];
  const int t = threadIdx.x;
  const int n0 = blockIdx.x * 64;
  const int k0 = blockIdx.y * 64;
#pragma unroll
  for (int i = 0; i < 4; ++i) {
    int row = i * 16 + (t >> 4);       // k within tile
    int col = (t & 15) * 4;            // n within tile
    float4 v = *(const float4*)(W + (size_t)(k0 + row) * 3072 + n0 + col);
    unsigned short h;
    h = f2bf(v.x); Th[row][col + 0] = h; Tl[row][col + 0] = f2bf(v.x - bf2f(h));
    h = f2bf(v.y); Th[row][col + 1] = h; Tl[row][col + 1] = f2bf(v.y - bf2f(h));
    h = f2bf(v.z); Th[row][col + 2] = h; Tl[row][col + 2] = f2bf(v.z - bf2f(h));
    h = f2bf(v.w); Th[row][col + 3] = h; Tl[row][col + 3] = f2bf(v.w - bf2f(h));
  }
  __syncthreads();
  const int rn = t & 63, qq = t >> 6;  // out row n0+rn, k-chunk qq*16
  unsigned int hw[8], lw[8];
#pragma unroll
  for (int j = 0; j < 8; ++j) {
    unsigned short a = Th[qq * 16 + 2 * j][rn], b = Th[qq * 16 + 2 * j + 1][rn];
    hw[j] = (unsigned int)a | ((unsigned int)b << 16);
    unsigned short c = Tl[qq * 16 + 2 * j][rn], d = Tl[qq * 16 + 2 * j + 1][rn];
    lw[j] = (unsigned int)c | ((unsigned int)d << 16);
  }
  size_t o = (size_t)(n0 + rn) * 1024 + k0 + qq * 16;
  *(uint4*)(wh + o)     = make_uint4(hw[0], hw[1], hw[2], hw[3]);
  *(uint4*)(wh + o + 8) = make_uint4(hw[4], hw[5], hw[6], hw[7]);
  *(uint4*)(wl + o)     = make_uint4(lw[0], lw[1], lw[2], lw[3]);
  *(uint4*)(wl + o + 8) = make_uint4(lw[4], lw[5], lw[6], lw[7]);
}

// ---------------------------------------------------------------------------
// K1: qkv = x @ Wqkv via bf16 hi/lo split MFMA (3 passes: hh, hl, lh).
// M=4096, N=3072, K=1024. 128x128 tile, BK=32, 4 waves, each wave 64x64
// (4x4 fragments of mfma_f32_16x16x32_bf16). Output scattered into q/k/v
// with layout [b][h][l][d].
// LDS tiles [128 rows][32 bf16] (64B rows); 16B-slot XOR swizzle
// s ^= (row>>1)&3 applied on BOTH the global source address (linear LDS dest,
// global_load_lds) and the ds_read side -> 2-way max bank aliasing (free).
// ---------------------------------------------------------------------------
__global__ __launch_bounds__(256, 2) void qkv_mfma(const unsigned short* __restrict__ xh,
                                                   const unsigned short* __restrict__ xl,
                                                   const unsigned short* __restrict__ wh,
                                                   const unsigned short* __restrict__ wl,
                                                   float* __restrict__ qarr,
                                                   float* __restrict__ karr,
                                                   float* __restrict__ varr) {
  __shared__ alignas(16) unsigned short Ah[128 * 32];
  __shared__ alignas(16) unsigned short Al[128 * 32];
  __shared__ alignas(16) unsigned short Bh[128 * 32];
  __shared__ alignas(16) unsigned short Bl[128 * 32];
  const int t = threadIdx.x;
  const int lane = t & 63;
  const int w = t >> 6;
  const int m0 = blockIdx.y * 128;
  const int n0 = blockIdx.x * 128;
  const int wr = w >> 1, wc = w & 1;
  const int l16 = lane & 15, s = lane >> 4;

  // staging: wave 0 -> Ah(xh,m0), 1 -> Al(xl,m0), 2 -> Bh(wh,n0), 3 -> Bl(wl,n0)
  const unsigned short* gsrc = (w == 0) ? xh : (w == 1) ? xl : (w == 2) ? wh : wl;
  unsigned short* lbase = (w == 0) ? Ah : (w == 1) ? Al : (w == 2) ? Bh : Bl;
  const int rbase = (w < 2) ? m0 : n0;
  const int srow = lane >> 2, sc = lane & 3;  // 16 rows x 4 chunks per 1KB issue

  // fragment byte offsets (k0-independent): row R, slot s, swizzled
  int aoff[4], boff[4];
#pragma unroll
  for (int f = 0; f < 4; ++f) {
    int Rm = wr * 64 + f * 16 + l16;
    aoff[f] = Rm * 64 + ((s ^ ((Rm >> 1) & 3)) << 4);
    int Rn = wc * 64 + f * 16 + l16;
    boff[f] = Rn * 64 + ((s ^ ((Rn >> 1) & 3)) << 4);
  }

  f32x4 acc[4][4];
#pragma unroll
  for (int i = 0; i < 4; ++i)
#pragma unroll
    for (int j = 0; j < 4; ++j) acc[i][j] = (f32x4){0.f, 0.f, 0.f, 0.f};

  const char* Ahc = (const char*)Ah;
  const char* Alc = (const char*)Al;
  const char* Bhc = (const char*)Bh;
  const char* Blc = (const char*)Bl;

  for (int k0 = 0; k0 < 1024; k0 += 32) {
    // each wave stages its 8KB array: 8 issues x 1KB (16 rows of 64B)
#pragma unroll
    for (int u = 0; u < 8; ++u) {
      int row = u * 16 + srow;
      int chunk = sc ^ ((row >> 1) & 3);  // pre-swizzled global source
      gload_lds16(gsrc + (size_t)(rbase + row) * 1024 + k0 + chunk * 8,
                  lbase + u * 512);
    }
    __syncthreads();

    bf16x8 a_h[4], a_l[4], b_h[4], b_l[4];
#pragma unroll
    for (int f = 0; f < 4; ++f) {
      a_h[f] = *(const bf16x8*)(Ahc + aoff[f]);
      b_h[f] = *(const bf16x8*)(Bhc + boff[f]);
    }
#pragma unroll
    for (int i = 0; i < 4; ++i)
#pragma unroll
      for (int j = 0; j < 4; ++j)
        acc[i][j] = __builtin_amdgcn_mfma_f32_16x16x32_bf16(a_h[i], b_h[j], acc[i][j], 0, 0, 0);
#pragma unroll
    for (int f = 0; f < 4; ++f) b_l[f] = *(const bf16x8*)(Blc + boff[f]);
#pragma unroll
    for (int i = 0; i < 4; ++i)
#pragma unroll
      for (int j = 0; j < 4; ++j)
        acc[i][j] = __builtin_amdgcn_mfma_f32_16x16x32_bf16(a_h[i], b_l[j], acc[i][j], 0, 0, 0);
#pragma unroll
    for (int f = 0; f < 4; ++f) a_l[f] = *(const bf16x8*)(Alc + aoff[f]);
#pragma unroll
    for (int i = 0; i < 4; ++i)
#pragma unroll
      for (int j = 0; j < 4; ++j)
        acc[i][j] = __builtin_amdgcn_mfma_f32_16x16x32_bf16(a_l[i], b_h[j], acc[i][j], 0, 0, 0);
    __syncthreads();
  }

  // epilogue: C/D layout col=lane&15, row=(lane>>4)*4+reg
  const int part = n0 >> 10;
  float* dst = (part == 0) ? qarr : (part == 1 ? karr : varr);
  const int nb = n0 & 1023;
#pragma unroll
  for (int i = 0; i < 4; ++i) {
#pragma unroll
    for (int j = 0; j < 4; ++j) {
      const int n = nb + wc * 64 + j * 16 + l16;
      const int h = n >> 6, d = n & 63;
#pragma unroll
      for (int r = 0; r < 4; ++r) {
        int m = m0 + wr * 64 + i * 16 + (lane >> 4) * 4 + r;
        int bb = m >> 9, l = m & 511;
        dst[(((size_t)(bb * Hn + h) * Ln + l) << 6) + d] = acc[i][j][r];
      }
    }
  }
}

// ---------------------------------------------------------------------------
// K2 (per batch): F[h] = (q[b,h]+r_w_bias[h]) @ R ; G[h] = k[b,h] @ R
// Per (h,which): (512x64)@(64x1024). Tile 64x64, K=64, 4x4/thread.
// ---------------------------------------------------------------------------
__global__ __launch_bounds__(256) void fg_gemm(const float* __restrict__ qarr,
                                               const float* __restrict__ karr,
                                               const float* __restrict__ rwb,
                                               const float* __restrict__ R,
                                               float* __restrict__ F,
                                               float* __restrict__ G,
                                               int b) {
  __shared__ float As[64][68];  // [k(d)][m]
  __shared__ float Rs[64][68];  // [k(d)][n]
  const int t = threadIdx.x;
  const int h = blockIdx.z >> 1;
  const int which = blockIdx.z & 1;  // 0 = F (q + r_w_bias), 1 = G (k)
  const int m0 = blockIdx.y * 64;
  const int n0 = blockIdx.x * 64;
  const float* A = (which == 0 ? qarr : karr) + (size_t)(b * Hn + h) * Ln * HD;

#pragma unroll
  for (int i = 0; i < 4; ++i) {
    int idx = t + i * 256;              // 0..1023
    int r = idx >> 4;                   // 0..63
    int c4 = (idx & 15) * 4;            // 0..60
    float4 av = *(const float4*)(A + (size_t)(m0 + r) * HD + c4);
    if (which == 0) {
      float4 bv = *(const float4*)(rwb + h * HD + c4);
      av.x += bv.x; av.y += bv.y; av.z += bv.z; av.w += bv.w;
    }
    As[c4 + 0][r] = av.x; As[c4 + 1][r] = av.y;
    As[c4 + 2][r] = av.z; As[c4 + 3][r] = av.w;
    *(float4*)(&Rs[r][c4]) = *(const float4*)(R + (size_t)r * TL + n0 + c4);
  }
  __syncthreads();
  const int tr = t >> 4, tc = t & 15;
  float acc[4][4];
#pragma unroll
  for (int i = 0; i < 4; ++i)
#pragma unroll
    for (int j = 0; j < 4; ++j) acc[i][j] = 0.f;
#pragma unroll 16
  for (int kk = 0; kk < 64; ++kk) {
    float a[4], bb[4];
    *(float4*)(a)  = *(const float4*)(&As[kk][tr * 4]);
    *(float4*)(bb) = *(const float4*)(&Rs[kk][tc * 4]);
#pragma unroll
    for (int i = 0; i < 4; ++i)
#pragma unroll
      for (int j = 0; j < 4; ++j) acc[i][j] = fmaf(a[i], bb[j], acc[i][j]);
  }
  float* O = (which == 0 ? F : G) + ((size_t)h * Ln + m0) * TL + n0;
#pragma unroll
  for (int i = 0; i < 4; ++i) {
    float4 v = make_float4(acc[i][0], acc[i][1], acc[i][2], acc[i][3]);
    *(float4*)(O + (size_t)(tr * 4 + i) * TL + tc * 4) = v;
  }
}

// ---------------------------------------------------------------------------
// K3 (per batch): fused scores + prev_out write + online softmax + P@V.
// Block: 16 q-rows of one (b,h); iterates 8 j-tiles of 64.
//   score[q,j] = ((q+r_r)·k[j] + F[q,512+j-q] + G[j,512+q-j]) / 8 + skip*prev
// ---------------------------------------------------------------------------
__global__ __launch_bounds__(256) void attn_fused(const float* __restrict__ qarr,
                                                  const float* __restrict__ karr,
                                                  const float* __restrict__ varr,
                                                  const float* __restrict__ rrb,
                                                  const float* __restrict__ F,
                                                  const float* __restrict__ G,
                                                  const float* __restrict__ prev,
                                                  const int* __restrict__ skip,
                                                  float* __restrict__ out,
                                                  float* __restrict__ pout,
                                                  int b) {
  __shared__ float qrT[64][18];   // [d][q]
  __shared__ float ktT[64][68];   // [d][j]
  __shared__ float vt[64][68];    // [j][d]
  __shared__ float St[16][68];    // scores then P
  __shared__ float red[16][16];
  __shared__ float mrun[16], lrun[16], mnew_s[16], alpha_s[16];

  const int t = threadIdx.x;
  const int h = blockIdx.y;
  const int q0 = blockIdx.x * 16;
  const float pf = (skip[0] != 0) ? 1.f : 0.f;
  const size_t bh = (size_t)(b * Hn + h);

  // stage qrT = q + r_r_bias, transposed [d][q]
  {
    int r = t >> 4, c4 = (t & 15) * 4;
    float4 av = *(const float4*)(qarr + (bh * Ln + q0 + r) * HD + c4);
    float4 bv = *(const float4*)(rrb + h * HD + c4);
    qrT[c4 + 0][r] = av.x + bv.x; qrT[c4 + 1][r] = av.y + bv.y;
    qrT[c4 + 2][r] = av.z + bv.z; qrT[c4 + 3][r] = av.w + bv.w;
  }
  if (t < 16) { mrun[t] = -INFINITY; lrun[t] = 0.f; }

  const int tq = t >> 4, tj = t & 15;  // score mapping: row tq, cols tj*4..+3
  const int d = t & 63, qg = t >> 6;   // PV mapping: col d, rows qg*4..+3
  float O[4] = {0.f, 0.f, 0.f, 0.f};

  for (int jt = 0; jt < 8; ++jt) {
    const int j0 = jt * 64;
    __syncthreads();  // protect previous tile's LDS (and qrT staging, iter 0)
#pragma unroll
    for (int i = 0; i < 4; ++i) {
      int idx = t + i * 256;
      int r = idx >> 4, c4 = (idx & 15) * 4;
      float4 kv = *(const float4*)(karr + (bh * Ln + j0 + r) * HD + c4);
      ktT[c4 + 0][r] = kv.x; ktT[c4 + 1][r] = kv.y;
      ktT[c4 + 2][r] = kv.z; ktT[c4 + 3][r] = kv.w;
      *(float4*)(&vt[r][c4]) = *(const float4*)(varr + (bh * Ln + j0 + r) * HD + c4);
    }
    __syncthreads();

    // AC partial: s[ji] = sum_d qr[tq][d]*k[tj*4+ji][d]
    float s[4] = {0.f, 0.f, 0.f, 0.f};
#pragma unroll 8
    for (int dd = 0; dd < 64; ++dd) {
      float a = qrT[dd][tq];
      float4 bv = *(const float4*)(&ktT[dd][tj * 4]);
      s[0] = fmaf(a, bv.x, s[0]);
      s[1] = fmaf(a, bv.y, s[1]);
      s[2] = fmaf(a, bv.z, s[2]);
      s[3] = fmaf(a, bv.w, s[3]);
    }
    // add F/G/prev, write prev_out (4 consecutive floats per thread)
    {
      const int q = q0 + tq;
      const size_t pbase = ((bh * Ln + q) << 9) + j0 + tj * 4;
      float4 pv4 = *(const float4*)(prev + pbase);
      const float pin[4] = {pv4.x, pv4.y, pv4.z, pv4.w};
      float4 o4;
      float* o4p = &o4.x;
#pragma unroll
      for (int ji = 0; ji < 4; ++ji) {
        const int j = j0 + tj * 4 + ji;
        float fv = F[((size_t)h * Ln + q) * TL + (Ln + j - q)];
        float gv = G[((size_t)h * Ln + j) * TL + (Ln + q - j)];
        float sc = (s[ji] + fv + gv) * 0.125f + pf * pin[ji];
        o4p[ji] = sc;
        s[ji] = sc;
        St[tq][tj * 4 + ji] = sc;
      }
      *(float4*)(pout + pbase) = o4;
    }
    __syncthreads();
    // tile row max
    {
      const int r = t >> 4, seg = t & 15;
      float mx = St[r][seg * 4];
#pragma unroll
      for (int u = 1; u < 4; ++u) mx = fmaxf(mx, St[r][seg * 4 + u]);
      red[r][seg] = mx;
    }
    __syncthreads();
    if (t < 16) {
      float mx = red[t][0];
#pragma unroll
      for (int u = 1; u < 16; ++u) mx = fmaxf(mx, red[t][u]);
      float mn = fmaxf(mrun[t], mx);
      alpha_s[t] = __expf(mrun[t] - mn);
      mnew_s[t] = mn;
      mrun[t] = mn;
    }
    __syncthreads();
    // P = exp(s - m_new)
    {
      const float mn = mnew_s[tq];
#pragma unroll
      for (int ji = 0; ji < 4; ++ji) St[tq][tj * 4 + ji] = __expf(s[ji] - mn);
    }
    __syncthreads();
    // tile row sum
    {
      const int r = t >> 4, seg = t & 15;
      float sm = 0.f;
#pragma unroll
      for (int u = 0; u < 4; ++u) sm += St[r][seg * 4 + u];
      red[r][seg] = sm;
    }
    __syncthreads();
    if (t < 16) {
      float sm = 0.f;
#pragma unroll
      for (int u = 0; u < 16; ++u) sm += red[t][u];
      lrun[t] = lrun[t] * alpha_s[t] + sm;
    }
    // O rescale + accumulate P@V
#pragma unroll
    for (int i = 0; i < 4; ++i) O[i] *= alpha_s[qg * 4 + i];
#pragma unroll 8
    for (int j = 0; j < 64; ++j) {
      float vv = vt[j][d];
#pragma unroll
      for (int i = 0; i < 4; ++i) O[i] = fmaf(St[qg * 4 + i][j], vv, O[i]);
    }
  }
  __syncthreads();
#pragma unroll
  for (int i = 0; i < 4; ++i) {
    int lq = qg * 4 + i;
    float val = O[i] / lrun[lq];
    out[((size_t)b * Ln + q0 + lq) * DM + h * HD + d] = val;
  }
}

// ---------------------------------------------------------------------------
// kernel_launch
// d_in (fp32 per reference): x, prev, Wqkv, r_r_bias, r_w_bias, rel_pos,
//                            skip_op(int)
// d_out (fp32): out (8*512*1024) then prev_out (8*16*512*512)
// ws layout (fp32): q | k | v | F_batch | G_batch   (= 117.4 MB)
// The bf16 hi/lo staging arrays (xh|xl|wh|wl, 29.4 MB) alias the F/G region:
// they are consumed by qkv_mfma before fg_gemm first writes F/G (stream order).
// ---------------------------------------------------------------------------
extern "C" void kernel_launch(void* const* d_in, const int* in_sizes, int n_in,
                              void* d_out, int out_size, void* d_ws, size_t ws_size,
                              hipStream_t stream) {
  const float* x    = (const float*)d_in[0];
  const float* prev = (const float*)d_in[1];
  const float* W    = (const float*)d_in[2];
  const float* rrb  = (const float*)d_in[3];
  const float* rwb  = (const float*)d_in[4];
  const float* R    = (const float*)d_in[5];
  const int*   skip = (const int*)d_in[6];

  float* out  = (float*)d_out;
  float* pout = out + (size_t)Bn * Ln * DM;

  float* ws = (float*)d_ws;
  float* qarr = ws;
  float* karr = ws + QS;
  float* varr = ws + 2 * QS;
  float* Farr = ws + 3 * QS;
  float* Garr = Farr + FSz;

  unsigned short* xh = (unsigned short*)Farr;  // aliased into F/G region
  unsigned short* xl = xh + QS;
  unsigned short* wh = xl + QS;
  unsigned short* wl = wh + WN;

  conv_x<<<dim3(4096), 256, 0, stream>>>(x, xh, xl);
  conv_w<<<dim3(48, 16), 256, 0, stream>>>(W, wh, wl);
  qkv_mfma<<<dim3(24, 32), 256, 0, stream>>>(xh, xl, wh, wl, qarr, karr, varr);
  for (int b = 0; b < Bn; ++b) {
    fg_gemm<<<dim3(TL / 64, Ln / 64, Hn * 2), 256, 0, stream>>>(qarr, karr, rwb, R, Farr, Garr, b);
    attn_fused<<<dim3(Ln / 16, Hn), 256, 0, stream>>>(qarr, karr, varr, rrb, Farr, Garr,
                                                      prev, skip, out, pout, b);
  }
}